// Round 2
// baseline (166.278 us; speedup 1.0000x reference)
//
#include <hip/hip_runtime.h>

#define NLVL 16
#define NPTS_PER_BLOCK 256

// Per-level constants from the reference's _level_params() (f64 math -> f32).
constexpr float SCALEC[NLVL] = {
    15.0f, 19.15873679831797f, 24.39841683149119f, 31.0f,
    39.31747359663594f, 49.79683366298238f, 63.0f, 79.63494719327189f,
    100.59366732596477f, 127.0f, 160.26989438654376f, 202.18733465192954f,
    255.0f, 321.5397887730875f, 405.3746693038591f, 511.0f
};
constexpr int RESC[NLVL] = {
    16, 21, 26, 32, 41, 51, 64, 81, 102, 128, 162, 204, 256, 323, 407, 512
};
constexpr int OFFC[NLVL] = {
    0, 4096, 13360, 30936, 63704, 132632, 265288, 527432,
    1051720, 1576008, 2100296, 2624584, 3148872, 3673160, 4197448, 4721736
};
// Levels 0..6: lin < res^3 <= hsize -> modulo is a no-op.
// Levels 7..15: hsize == 2^19      -> lin & 0x7FFFF (pair may wrap at the mask).
constexpr int HMASK = 0x7FFFF;

struct Lvl {
    float4 p00, p10, p01, p11;   // x-pairs for (iy,iz) = (0,0),(1,0),(0,1),(1,1)
    float tx, ty, tz;
};

// Load the x-adjacent corner pair (elements lin&mask, (lin+1)&mask of level L)
// as one 16-B load. Rare wrap case handled on a divergent side path.
template<int L>
__device__ inline float4 pair_load(const float2* __restrict__ tab, int lin) {
    constexpr int off = OFFC[L];
    float4 p;
    if constexpr (L >= 7) {
        const int e0 = lin & HMASK;
        if (__builtin_expect(e0 == HMASK, 0)) {
            const float2 a = tab[off + HMASK];
            const float2 b = tab[off];            // wrapped second element
            p.x = a.x; p.y = a.y; p.z = b.x; p.w = b.y;
        } else {
            __builtin_memcpy(&p, tab + off + e0, 16);   // 8B-aligned 16B load
        }
    } else {
        __builtin_memcpy(&p, tab + off + lin, 16);
    }
    return p;
}

template<int L>
__device__ inline Lvl load_level(float x, float y, float z,
                                 const float2* __restrict__ tab) {
    constexpr float s = SCALEC[L];
    constexpr int   r = RESC[L];
    const float px = x * s, py = y * s, pz = z * s;
    const float fx = floorf(px), fy = floorf(py), fz = floorf(pz);
    Lvl d;
    d.tx = px - fx; d.ty = py - fy; d.tz = pz - fz;
    const int bx = (int)fx, by = (int)fy, bz = (int)fz;
    const int lin = bx + r * by + r * r * bz;
    d.p00 = pair_load<L>(tab, lin);
    d.p10 = pair_load<L>(tab, lin + r);
    d.p01 = pair_load<L>(tab, lin + r * r);
    d.p11 = pair_load<L>(tab, lin + r * r + r);
    return d;
}

__device__ inline void accum_level(const Lvl& d, float* __restrict__ e) {
    const float wx1 = d.tx, wx0 = 1.0f - d.tx;
    const float wy1 = d.ty, wy0 = 1.0f - d.ty;
    const float wz1 = d.tz, wz0 = 1.0f - d.tz;
    const float w00 = wy0 * wz0, w10 = wy1 * wz0;
    const float w01 = wy0 * wz1, w11 = wy1 * wz1;
    float a0 = 0.0f, a1 = 0.0f;
    a0 = fmaf(w00 * wx0, d.p00.x, a0); a1 = fmaf(w00 * wx0, d.p00.y, a1);
    a0 = fmaf(w00 * wx1, d.p00.z, a0); a1 = fmaf(w00 * wx1, d.p00.w, a1);
    a0 = fmaf(w10 * wx0, d.p10.x, a0); a1 = fmaf(w10 * wx0, d.p10.y, a1);
    a0 = fmaf(w10 * wx1, d.p10.z, a0); a1 = fmaf(w10 * wx1, d.p10.w, a1);
    a0 = fmaf(w01 * wx0, d.p01.x, a0); a1 = fmaf(w01 * wx0, d.p01.y, a1);
    a0 = fmaf(w01 * wx1, d.p01.z, a0); a1 = fmaf(w01 * wx1, d.p01.w, a1);
    a0 = fmaf(w11 * wx0, d.p11.x, a0); a1 = fmaf(w11 * wx0, d.p11.y, a1);
    a0 = fmaf(w11 * wx1, d.p11.z, a0); a1 = fmaf(w11 * wx1, d.p11.w, a1);
    e[0] = a0; e[1] = a1;
}

__global__ __launch_bounds__(NPTS_PER_BLOCK)
void hashgrid_mlp_kernel(const float* __restrict__ coords,   // [N,3]
                         const float* __restrict__ emb,      // [total,2]
                         const float* __restrict__ W0,       // [32,32]
                         const float* __restrict__ b0,       // [32]
                         const float* __restrict__ W1,       // [32,32]
                         const float* __restrict__ b1,       // [32]
                         const float* __restrict__ W2,       // [32,1]
                         const float* __restrict__ b2,       // [1]
                         float* __restrict__ out,            // [N]
                         int n)
{
    const int tid = blockIdx.x * blockDim.x + threadIdx.x;
    if (tid >= n) return;

    const float x = (coords[tid * 3 + 0] + 1.0f) * 0.5f;
    const float y = (coords[tid * 3 + 1] + 1.0f) * 0.5f;
    const float z = (coords[tid * 3 + 2] + 1.0f) * 0.5f;

    const float2* __restrict__ tab = (const float2*)emb;

    float enc[2 * NLVL];

    // Depth-2 software pipeline: level L+1's loads in flight while accumulating L.
    Lvl cur = load_level<0>(x, y, z, tab);
#define STEP(L) { Lvl nxt = load_level<L>(x, y, z, tab); \
                  accum_level(cur, &enc[2 * ((L) - 1)]); cur = nxt; }
    STEP(1)  STEP(2)  STEP(3)  STEP(4)  STEP(5)  STEP(6)  STEP(7)
    STEP(8)  STEP(9)  STEP(10) STEP(11) STEP(12) STEP(13) STEP(14) STEP(15)
#undef STEP
    accum_level(cur, &enc[30]);

    // ---- MLP: 32 -> 32 (leaky 0.01) -> 32 (leaky 0.01) -> 1 ----
    // Uniform weight addresses -> s_load into SGPRs, no per-lane traffic.
    float h0[32];
#pragma unroll
    for (int j = 0; j < 32; ++j) h0[j] = b0[j];
#pragma unroll
    for (int i = 0; i < 32; ++i) {
        const float e = enc[i];
#pragma unroll
        for (int j = 0; j < 32; ++j) h0[j] = fmaf(e, W0[i * 32 + j], h0[j]);
    }
#pragma unroll
    for (int j = 0; j < 32; ++j) h0[j] = (h0[j] >= 0.0f) ? h0[j] : 0.01f * h0[j];

    float h1[32];
#pragma unroll
    for (int j = 0; j < 32; ++j) h1[j] = b1[j];
#pragma unroll
    for (int i = 0; i < 32; ++i) {
        const float e = h0[i];
#pragma unroll
        for (int j = 0; j < 32; ++j) h1[j] = fmaf(e, W1[i * 32 + j], h1[j]);
    }
#pragma unroll
    for (int j = 0; j < 32; ++j) h1[j] = (h1[j] >= 0.0f) ? h1[j] : 0.01f * h1[j];

    float acc = b2[0];
#pragma unroll
    for (int j = 0; j < 32; ++j) acc = fmaf(h1[j], W2[j], acc);

    out[tid] = acc;
}

extern "C" void kernel_launch(void* const* d_in, const int* in_sizes, int n_in,
                              void* d_out, int out_size, void* d_ws, size_t ws_size,
                              hipStream_t stream) {
    const float* coords = (const float*)d_in[0];   // [N,1,3]
    const float* emb    = (const float*)d_in[1];   // [total,1,2]
    const float* W0     = (const float*)d_in[2];
    const float* b0     = (const float*)d_in[3];
    const float* W1     = (const float*)d_in[4];
    const float* b1     = (const float*)d_in[5];
    const float* W2     = (const float*)d_in[6];
    const float* b2     = (const float*)d_in[7];
    float* out = (float*)d_out;

    const int n = in_sizes[0] / 3;   // 262144
    const int blocks = (n + NPTS_PER_BLOCK - 1) / NPTS_PER_BLOCK;
    hashgrid_mlp_kernel<<<blocks, NPTS_PER_BLOCK, 0, stream>>>(
        coords, emb, W0, b0, W1, b1, W2, b2, out, n);
}

// Round 3
// 99.779 us; speedup vs baseline: 1.6665x; 1.6665x over previous
//
#include <hip/hip_runtime.h>

#define NLVL 16
#define NPTS_PER_BLOCK 256

// Per-level constants from the reference's _level_params() (f64 math -> f32).
constexpr float SCALEC[NLVL] = {
    15.0f, 19.15873679831797f, 24.39841683149119f, 31.0f,
    39.31747359663594f, 49.79683366298238f, 63.0f, 79.63494719327189f,
    100.59366732596477f, 127.0f, 160.26989438654376f, 202.18733465192954f,
    255.0f, 321.5397887730875f, 405.3746693038591f, 511.0f
};
constexpr int RESC[NLVL] = {
    16, 21, 26, 32, 41, 51, 64, 81, 102, 128, 162, 204, 256, 323, 407, 512
};
constexpr int OFFC[NLVL] = {
    0, 4096, 13360, 30936, 63704, 132632, 265288, 527432,
    1051720, 1576008, 2100296, 2624584, 3148872, 3673160, 4197448, 4721736
};
// Levels 0..6: lin < res^3 <= hsize -> modulo is a no-op.
// Levels 7..15: hsize == 2^19      -> lin & 0x7FFFF; the x-pair (e0,e0+1)
// wraps when e0 == 0x7FFFF -> branchless cndmask fix with uniform tab[off].
constexpr int HMASK = 0x7FFFF;

// Issue level L's 4 pair-loads (each a 16-B load of two adjacent float2
// entries) into q00..q11; record fracs. Branchless wrap fix for L>=7.
template<int L>
__device__ __forceinline__ void level_issue(float x, float y, float z,
                                            const float* __restrict__ emb,
                                            float4& q00, float4& q10,
                                            float4& q01, float4& q11,
                                            float& tx, float& ty, float& tz)
{
    constexpr float s = SCALEC[L];
    constexpr int   r = RESC[L];
    constexpr int   off = OFFC[L];

    const float px = x * s, py = y * s, pz = z * s;
    const float fx = floorf(px), fy = floorf(py), fz = floorf(pz);
    tx = px - fx; ty = py - fy; tz = pz - fz;
    const int lin = (int)fx + r * (int)fy + r * r * (int)fz;

    int i00 = lin, i10 = lin + r, i01 = lin + r * r, i11 = lin + r * r + r;
    if constexpr (L >= 7) {
        i00 &= HMASK; i10 &= HMASK; i01 &= HMASK; i11 &= HMASK;
    }
    __builtin_memcpy(&q00, emb + 2 * (off + i00), 16);
    __builtin_memcpy(&q10, emb + 2 * (off + i10), 16);
    __builtin_memcpy(&q01, emb + 2 * (off + i01), 16);
    __builtin_memcpy(&q11, emb + 2 * (off + i11), 16);
    if constexpr (L >= 7) {
        // Uniform address -> s_load, no per-lane traffic.
        const float f0x = emb[2 * off], f0y = emb[2 * off + 1];
        q00.z = (i00 == HMASK) ? f0x : q00.z;  q00.w = (i00 == HMASK) ? f0y : q00.w;
        q10.z = (i10 == HMASK) ? f0x : q10.z;  q10.w = (i10 == HMASK) ? f0y : q10.w;
        q01.z = (i01 == HMASK) ? f0x : q01.z;  q01.w = (i01 == HMASK) ? f0y : q01.w;
        q11.z = (i11 == HMASK) ? f0x : q11.z;  q11.w = (i11 == HMASK) ? f0y : q11.w;
    }
}

// Trilinear-accumulate level L, then fuse its two encoder channels straight
// into the first MLP layer (rows 2L, 2L+1 of W0; uniform -> SGPR-resident).
template<int L>
__device__ __forceinline__ void level_accum(const float4& q00, const float4& q10,
                                            const float4& q01, const float4& q11,
                                            float tx, float ty, float tz,
                                            float* __restrict__ h0,
                                            const float* __restrict__ W0)
{
    const float wx1 = tx, wx0 = 1.0f - tx;
    const float wy1 = ty, wy0 = 1.0f - ty;
    const float wz1 = tz, wz0 = 1.0f - tz;
    const float w00 = wy0 * wz0, w10 = wy1 * wz0;
    const float w01 = wy0 * wz1, w11 = wy1 * wz1;
    float a0 = 0.0f, a1 = 0.0f;
    a0 = fmaf(w00 * wx0, q00.x, a0); a1 = fmaf(w00 * wx0, q00.y, a1);
    a0 = fmaf(w00 * wx1, q00.z, a0); a1 = fmaf(w00 * wx1, q00.w, a1);
    a0 = fmaf(w10 * wx0, q10.x, a0); a1 = fmaf(w10 * wx0, q10.y, a1);
    a0 = fmaf(w10 * wx1, q10.z, a0); a1 = fmaf(w10 * wx1, q10.w, a1);
    a0 = fmaf(w01 * wx0, q01.x, a0); a1 = fmaf(w01 * wx0, q01.y, a1);
    a0 = fmaf(w01 * wx1, q01.z, a0); a1 = fmaf(w01 * wx1, q01.w, a1);
    a0 = fmaf(w11 * wx0, q11.x, a0); a1 = fmaf(w11 * wx0, q11.y, a1);
    a0 = fmaf(w11 * wx1, q11.z, a0); a1 = fmaf(w11 * wx1, q11.w, a1);
#pragma unroll
    for (int j = 0; j < 32; ++j)
        h0[j] = fmaf(a0, W0[(2 * L + 0) * 32 + j], h0[j]);
#pragma unroll
    for (int j = 0; j < 32; ++j)
        h0[j] = fmaf(a1, W0[(2 * L + 1) * 32 + j], h0[j]);
}

__global__ __launch_bounds__(NPTS_PER_BLOCK, 4)   // cap VGPR at 128: keep 4 waves/SIMD
void hashgrid_mlp_kernel(const float* __restrict__ coords,   // [N,3]
                         const float* __restrict__ emb,      // [total,2]
                         const float* __restrict__ W0,       // [32,32]
                         const float* __restrict__ b0,       // [32]
                         const float* __restrict__ W1,       // [32,32]
                         const float* __restrict__ b1,       // [32]
                         const float* __restrict__ W2,       // [32,1]
                         const float* __restrict__ b2,       // [1]
                         float* __restrict__ out,            // [N]
                         int n)
{
    const int tid = blockIdx.x * blockDim.x + threadIdx.x;
    if (tid >= n) return;

    const float x = (coords[tid * 3 + 0] + 1.0f) * 0.5f;
    const float y = (coords[tid * 3 + 1] + 1.0f) * 0.5f;
    const float z = (coords[tid * 3 + 2] + 1.0f) * 0.5f;

    float h0[32];
#pragma unroll
    for (int j = 0; j < 32; ++j) h0[j] = b0[j];

    // Depth-2 manual pipeline with two explicit register sets A and B:
    // issue L+1's loads while level L's loads are in flight, then accumulate L.
    float4 a00, a10, a01, a11; float atx, aty, atz;
    float4 b00, b10, b01, b11; float btx, bty, btz;

#define ISSUE_A(L) level_issue<L>(x, y, z, emb, a00, a10, a01, a11, atx, aty, atz);
#define ISSUE_B(L) level_issue<L>(x, y, z, emb, b00, b10, b01, b11, btx, bty, btz);
#define ACC_A(L)   level_accum<L>(a00, a10, a01, a11, atx, aty, atz, h0, W0);
#define ACC_B(L)   level_accum<L>(b00, b10, b01, b11, btx, bty, btz, h0, W0);

    ISSUE_A(0)
    ISSUE_B(1)  ACC_A(0)
    ISSUE_A(2)  ACC_B(1)
    ISSUE_B(3)  ACC_A(2)
    ISSUE_A(4)  ACC_B(3)
    ISSUE_B(5)  ACC_A(4)
    ISSUE_A(6)  ACC_B(5)
    ISSUE_B(7)  ACC_A(6)
    ISSUE_A(8)  ACC_B(7)
    ISSUE_B(9)  ACC_A(8)
    ISSUE_A(10) ACC_B(9)
    ISSUE_B(11) ACC_A(10)
    ISSUE_A(12) ACC_B(11)
    ISSUE_B(13) ACC_A(12)
    ISSUE_A(14) ACC_B(13)
    ISSUE_B(15) ACC_A(14)
    ACC_B(15)

#undef ISSUE_A
#undef ISSUE_B
#undef ACC_A
#undef ACC_B

#pragma unroll
    for (int j = 0; j < 32; ++j) h0[j] = (h0[j] >= 0.0f) ? h0[j] : 0.01f * h0[j];

    float h1[32];
#pragma unroll
    for (int j = 0; j < 32; ++j) h1[j] = b1[j];
#pragma unroll
    for (int i = 0; i < 32; ++i) {
        const float e = h0[i];
#pragma unroll
        for (int j = 0; j < 32; ++j) h1[j] = fmaf(e, W1[i * 32 + j], h1[j]);
    }
#pragma unroll
    for (int j = 0; j < 32; ++j) h1[j] = (h1[j] >= 0.0f) ? h1[j] : 0.01f * h1[j];

    float acc = b2[0];
#pragma unroll
    for (int j = 0; j < 32; ++j) acc = fmaf(h1[j], W2[j], acc);

    out[tid] = acc;
}

extern "C" void kernel_launch(void* const* d_in, const int* in_sizes, int n_in,
                              void* d_out, int out_size, void* d_ws, size_t ws_size,
                              hipStream_t stream) {
    const float* coords = (const float*)d_in[0];   // [N,1,3]
    const float* emb    = (const float*)d_in[1];   // [total,1,2]
    const float* W0     = (const float*)d_in[2];
    const float* b0     = (const float*)d_in[3];
    const float* W1     = (const float*)d_in[4];
    const float* b1     = (const float*)d_in[5];
    const float* W2     = (const float*)d_in[6];
    const float* b2     = (const float*)d_in[7];
    float* out = (float*)d_out;

    const int n = in_sizes[0] / 3;   // 262144
    const int blocks = (n + NPTS_PER_BLOCK - 1) / NPTS_PER_BLOCK;
    hashgrid_mlp_kernel<<<blocks, NPTS_PER_BLOCK, 0, stream>>>(
        coords, emb, W0, b0, W1, b1, W2, b2, out, n);
}

// Round 4
// 98.712 us; speedup vs baseline: 1.6845x; 1.0108x over previous
//
#include <hip/hip_runtime.h>

#define NLVL 16
#define NPTS_PER_BLOCK 256

// Per-level constants from the reference's _level_params() (f64 math -> f32).
constexpr float SCALEC[NLVL] = {
    15.0f, 19.15873679831797f, 24.39841683149119f, 31.0f,
    39.31747359663594f, 49.79683366298238f, 63.0f, 79.63494719327189f,
    100.59366732596477f, 127.0f, 160.26989438654376f, 202.18733465192954f,
    255.0f, 321.5397887730875f, 405.3746693038591f, 511.0f
};
constexpr int RESC[NLVL] = {
    16, 21, 26, 32, 41, 51, 64, 81, 102, 128, 162, 204, 256, 323, 407, 512
};
constexpr int OFFC[NLVL] = {
    0, 4096, 13360, 30936, 63704, 132632, 265288, 527432,
    1051720, 1576008, 2100296, 2624584, 3148872, 3673160, 4197448, 4721736
};
// Levels 0..6: lin < res^3 <= hsize -> modulo is a no-op.
// Levels 7..15: hsize == 2^19      -> lin & 0x7FFFF; x-pair (e0,e0+1) wraps
// when e0 == 0x7FFFF -> fixed at ACC time via cndmask with uniform tab[off].
constexpr int HMASK = 0x7FFFF;

// ISSUE: indices + 4x 16-B loads only. Nothing here reads load results, so
// the compiler's vmcnt wait lands in level_accum, keeping loads in flight.
template<int L>
__device__ __forceinline__ void level_issue(float x, float y, float z,
                                            const float* __restrict__ emb,
                                            float4& q00, float4& q10,
                                            float4& q01, float4& q11,
                                            int& wmask)
{
    constexpr float s = SCALEC[L];
    constexpr int   r = RESC[L];
    constexpr int   off = OFFC[L];

    const float px = x * s, py = y * s, pz = z * s;
    const int bx = (int)floorf(px), by = (int)floorf(py), bz = (int)floorf(pz);
    const int lin = bx + r * by + r * r * bz;

    int i00 = lin, i10 = lin + r, i01 = lin + r * r, i11 = lin + r * r + r;
    if constexpr (L >= 7) {
        i00 &= HMASK; i10 &= HMASK; i01 &= HMASK; i11 &= HMASK;
        wmask = (i00 == HMASK ? 1 : 0) | (i10 == HMASK ? 2 : 0)
              | (i01 == HMASK ? 4 : 0) | (i11 == HMASK ? 8 : 0);
    } else {
        wmask = 0;
    }
    __builtin_memcpy(&q00, emb + 2 * (off + i00), 16);
    __builtin_memcpy(&q10, emb + 2 * (off + i10), 16);
    __builtin_memcpy(&q01, emb + 2 * (off + i01), 16);
    __builtin_memcpy(&q11, emb + 2 * (off + i11), 16);
}

// ACC: recompute fracs (cheap VALU, saves live regs), apply the rare-wrap
// cndmask fix, trilinear-accumulate, and fuse into MLP layer 0 (rows 2L,2L+1
// of W0 stream through SGPRs - uniform addresses).
template<int L>
__device__ __forceinline__ void level_accum(float x, float y, float z,
                                            const float* __restrict__ emb,
                                            float4 q00, float4 q10,
                                            float4 q01, float4 q11,
                                            int wmask,
                                            float* __restrict__ h0,
                                            const float* __restrict__ W0)
{
    constexpr float s = SCALEC[L];
    constexpr int   off = OFFC[L];

    const float px = x * s, py = y * s, pz = z * s;
    const float tx = px - floorf(px), ty = py - floorf(py), tz = pz - floorf(pz);

    if constexpr (L >= 7) {
        const float f0x = emb[2 * off], f0y = emb[2 * off + 1];  // uniform s_load
        q00.z = (wmask & 1) ? f0x : q00.z;  q00.w = (wmask & 1) ? f0y : q00.w;
        q10.z = (wmask & 2) ? f0x : q10.z;  q10.w = (wmask & 2) ? f0y : q10.w;
        q01.z = (wmask & 4) ? f0x : q01.z;  q01.w = (wmask & 4) ? f0y : q01.w;
        q11.z = (wmask & 8) ? f0x : q11.z;  q11.w = (wmask & 8) ? f0y : q11.w;
    }

    const float wx1 = tx, wx0 = 1.0f - tx;
    const float wy1 = ty, wy0 = 1.0f - ty;
    const float wz1 = tz, wz0 = 1.0f - tz;
    const float w00 = wy0 * wz0, w10 = wy1 * wz0;
    const float w01 = wy0 * wz1, w11 = wy1 * wz1;
    float a0 = 0.0f, a1 = 0.0f;
    a0 = fmaf(w00 * wx0, q00.x, a0); a1 = fmaf(w00 * wx0, q00.y, a1);
    a0 = fmaf(w00 * wx1, q00.z, a0); a1 = fmaf(w00 * wx1, q00.w, a1);
    a0 = fmaf(w10 * wx0, q10.x, a0); a1 = fmaf(w10 * wx0, q10.y, a1);
    a0 = fmaf(w10 * wx1, q10.z, a0); a1 = fmaf(w10 * wx1, q10.w, a1);
    a0 = fmaf(w01 * wx0, q01.x, a0); a1 = fmaf(w01 * wx0, q01.y, a1);
    a0 = fmaf(w01 * wx1, q01.z, a0); a1 = fmaf(w01 * wx1, q01.w, a1);
    a0 = fmaf(w11 * wx0, q11.x, a0); a1 = fmaf(w11 * wx0, q11.y, a1);
    a0 = fmaf(w11 * wx1, q11.z, a0); a1 = fmaf(w11 * wx1, q11.w, a1);

#pragma unroll
    for (int j = 0; j < 32; ++j)
        h0[j] = fmaf(a0, W0[(2 * L + 0) * 32 + j], h0[j]);
#pragma unroll
    for (int j = 0; j < 32; ++j)
        h0[j] = fmaf(a1, W0[(2 * L + 1) * 32 + j], h0[j]);
}

__global__ __launch_bounds__(NPTS_PER_BLOCK, 4)   // cap VGPR at 128 (4 waves/SIMD)
void hashgrid_mlp_kernel(const float* __restrict__ coords,   // [N,3]
                         const float* __restrict__ emb,      // [total,2]
                         const float* __restrict__ W0,       // [32,32]
                         const float* __restrict__ b0,       // [32]
                         const float* __restrict__ W1,       // [32,32]
                         const float* __restrict__ b1,       // [32]
                         const float* __restrict__ W2,       // [32,1]
                         const float* __restrict__ b2,       // [1]
                         float* __restrict__ out,            // [N]
                         int n)
{
    const int tid = blockIdx.x * blockDim.x + threadIdx.x;
    if (tid >= n) return;

    const float x = (coords[tid * 3 + 0] + 1.0f) * 0.5f;
    const float y = (coords[tid * 3 + 1] + 1.0f) * 0.5f;
    const float z = (coords[tid * 3 + 2] + 1.0f) * 0.5f;

    float h0[32];
#pragma unroll
    for (int j = 0; j < 32; ++j) h0[j] = b0[j];

    // Depth-4 rotating pipeline: while accumulating level L, levels
    // L+1..L+3 (12 vector loads) stay in flight.
    float4 a00, a10, a01, a11; int am;
    float4 b00, b10, b01, b11; int bm;
    float4 c00, c10, c01, c11; int cm;
    float4 d00, d10, d01, d11; int dm;

#define ISS(S, L) level_issue<L>(x, y, z, emb, S##00, S##10, S##01, S##11, S##m);
#define ACC(S, L) level_accum<L>(x, y, z, emb, S##00, S##10, S##01, S##11, S##m, h0, W0);

    ISS(a, 0) ISS(b, 1) ISS(c, 2) ISS(d, 3)
    ACC(a, 0)  ISS(a, 4)
    ACC(b, 1)  ISS(b, 5)
    ACC(c, 2)  ISS(c, 6)
    ACC(d, 3)  ISS(d, 7)
    ACC(a, 4)  ISS(a, 8)
    ACC(b, 5)  ISS(b, 9)
    ACC(c, 6)  ISS(c, 10)
    ACC(d, 7)  ISS(d, 11)
    ACC(a, 8)  ISS(a, 12)
    ACC(b, 9)  ISS(b, 13)
    ACC(c, 10) ISS(c, 14)
    ACC(d, 11) ISS(d, 15)
    ACC(a, 12)
    ACC(b, 13)
    ACC(c, 14)
    ACC(d, 15)

#undef ISS
#undef ACC

#pragma unroll
    for (int j = 0; j < 32; ++j) h0[j] = (h0[j] >= 0.0f) ? h0[j] : 0.01f * h0[j];

    float h1[32];
#pragma unroll
    for (int j = 0; j < 32; ++j) h1[j] = b1[j];
#pragma unroll
    for (int i = 0; i < 32; ++i) {
        const float e = h0[i];
#pragma unroll
        for (int j = 0; j < 32; ++j) h1[j] = fmaf(e, W1[i * 32 + j], h1[j]);
    }
#pragma unroll
    for (int j = 0; j < 32; ++j) h1[j] = (h1[j] >= 0.0f) ? h1[j] : 0.01f * h1[j];

    float acc = b2[0];
#pragma unroll
    for (int j = 0; j < 32; ++j) acc = fmaf(h1[j], W2[j], acc);

    out[tid] = acc;
}

extern "C" void kernel_launch(void* const* d_in, const int* in_sizes, int n_in,
                              void* d_out, int out_size, void* d_ws, size_t ws_size,
                              hipStream_t stream) {
    const float* coords = (const float*)d_in[0];   // [N,1,3]
    const float* emb    = (const float*)d_in[1];   // [total,1,2]
    const float* W0     = (const float*)d_in[2];
    const float* b0     = (const float*)d_in[3];
    const float* W1     = (const float*)d_in[4];
    const float* b1     = (const float*)d_in[5];
    const float* W2     = (const float*)d_in[6];
    const float* b2     = (const float*)d_in[7];
    float* out = (float*)d_out;

    const int n = in_sizes[0] / 3;   // 262144
    const int blocks = (n + NPTS_PER_BLOCK - 1) / NPTS_PER_BLOCK;
    hashgrid_mlp_kernel<<<blocks, NPTS_PER_BLOCK, 0, stream>>>(
        coords, emb, W0, b0, W1, b1, W2, b2, out, n);
}